// Round 6
// baseline (205.152 us; speedup 1.0000x reference)
//
#include <hip/hip_runtime.h>
#include <hip/hip_bf16.h>
#include <math.h>

#define DEP   96
#define HEADS 96
#define BSZ   16
#define DIM   512
#define REL   128
#define RELP  129   // REL + nil

typedef __attribute__((ext_vector_type(8))) short     short8;   // 8 bf16
typedef __attribute__((ext_vector_type(8))) _Float16  half8;    // 8 fp16
typedef __attribute__((ext_vector_type(4))) float     floatx4;

__device__ __forceinline__ unsigned short f2bf(float x) {
    union { float f; unsigned int u; } c; c.f = x;
    unsigned int r = c.u + 0x7fffu + ((c.u >> 16) & 1u);   // RNE
    return (unsigned short)(r >> 16);
}
__device__ __forceinline__ unsigned short f2h(float x) {
    union { _Float16 h; unsigned short u; } c;
    c.h = (_Float16)x;                                     // v_cvt_f16_f32 (RNE)
    return c.u;
}
// packed fp16 add / relu via VOP3P (bulletproof vs header availability)
__device__ __forceinline__ unsigned pk_add_h2(unsigned a, unsigned b) {
    unsigned r; asm("v_pk_add_f16 %0, %1, %2" : "=v"(r) : "v"(a), "v"(b)); return r;
}
__device__ __forceinline__ unsigned pk_max_h2(unsigned a, unsigned b) {
    unsigned r; asm("v_pk_max_f16 %0, %1, %2" : "=v"(r) : "v"(a), "v"(b)); return r;
}

// ---------------------------------------------------------------------------
// Kernel 0: weight conversion. Wt -> bf16 (proj MFMA), Wp -> fp16 (fused).
// 73728 chunks x 8 elems: [0,65536) -> Wt, rest -> Wp.
// ---------------------------------------------------------------------------
__global__ __launch_bounds__(256) void cvt_kernel(
    const float* __restrict__ Wt, const float* __restrict__ Wp,
    unsigned short* __restrict__ WtB, unsigned short* __restrict__ WpH)
{
    const int chunk = blockIdx.x * 256 + threadIdx.x;
    if (chunk < 65536) {
        const int c = chunk;
        float4 a = *(const float4*)(Wt + (size_t)c * 8);
        float4 b = *(const float4*)(Wt + (size_t)c * 8 + 4);
        uint4 o;
        o.x = (unsigned)f2bf(a.x) | ((unsigned)f2bf(a.y) << 16);
        o.y = (unsigned)f2bf(a.z) | ((unsigned)f2bf(a.w) << 16);
        o.z = (unsigned)f2bf(b.x) | ((unsigned)f2bf(b.y) << 16);
        o.w = (unsigned)f2bf(b.z) | ((unsigned)f2bf(b.w) << 16);
        *(uint4*)(WtB + (size_t)c * 8) = o;
    } else {
        const int c = chunk - 65536;
        float4 a = *(const float4*)(Wp + (size_t)c * 8);
        float4 b = *(const float4*)(Wp + (size_t)c * 8 + 4);
        uint4 o;
        o.x = (unsigned)f2h(a.x) | ((unsigned)f2h(a.y) << 16);
        o.y = (unsigned)f2h(a.z) | ((unsigned)f2h(a.w) << 16);
        o.z = (unsigned)f2h(b.x) | ((unsigned)f2h(b.y) << 16);
        o.w = (unsigned)f2h(b.z) | ((unsigned)f2h(b.w) << 16);
        *(uint4*)(WpH + (size_t)c * 8) = o;
    }
}

#define PSS 72   // LDS row stride (bf16 elems): 144 B = 16B-aligned

// ---------------------------------------------------------------------------
// Kernel A: projections via bf16 MFMA. A cast-on-stage (f32 in), Wt pre-cast.
//   z=0: P1[m][n] = outs@Wt[:, :512]^T + bt   (f32 out)
//   z=1: P2H[m][n]= graph@Wt[:, 512:]^T       (fp16 out, for fused pk-math)
// ---------------------------------------------------------------------------
__global__ __launch_bounds__(256) void proj_kernel(
    const float* __restrict__ outs, const float* __restrict__ graph,
    const unsigned short* __restrict__ WtB, const float* __restrict__ bt,
    float* __restrict__ P1, unsigned short* __restrict__ P2H)
{
    const int z = blockIdx.z;
    const float* A = z ? graph : outs;
    const int off  = z ? DIM : 0;
    const int row0 = blockIdx.y * 64;
    const int col0 = blockIdx.x * 64;

    __shared__ unsigned short As[64 * PSS];   // [m][k] bf16
    __shared__ unsigned short Ws[64 * PSS];   // [n][k] bf16

    const int tid  = threadIdx.x;
    const int lane = tid & 63;
    const int wv   = tid >> 6;          // 0..3
    const int ln15 = lane & 15;
    const int quad = lane >> 4;

    floatx4 acc[4];
    #pragma unroll
    for (int nt = 0; nt < 4; ++nt) acc[nt] = (floatx4){0.f,0.f,0.f,0.f};

    for (int kt = 0; kt < DIM; kt += 64) {
        #pragma unroll
        for (int q = 0; q < 4; ++q) {
            const int slot = q*256 + tid;       // 0..1023
            const int r  = slot >> 4;           // 0..63
            const int e4 = (slot & 15) * 4;
            float4 v = *(const float4*)(A + (size_t)(row0 + r) * DIM + kt + e4);
            ushort4 o;
            o.x = f2bf(v.x); o.y = f2bf(v.y); o.z = f2bf(v.z); o.w = f2bf(v.w);
            *(ushort4*)&As[r * PSS + e4] = o;
        }
        #pragma unroll
        for (int q = 0; q < 2; ++q) {
            const int slot = q*256 + tid;       // 0..511
            const int r  = slot >> 3;           // 0..63
            const int e8 = (slot & 7) * 8;
            *(uint4*)&Ws[r * PSS + e8] =
                *(const uint4*)(WtB + (size_t)(col0 + r) * (2*DIM) + off + kt + e8);
        }
        __syncthreads();
        #pragma unroll
        for (int ks = 0; ks < 64; ks += 32) {
            short8 af = *(const short8*)&As[(wv*16 + ln15) * PSS + ks + quad*8];
            #pragma unroll
            for (int nt = 0; nt < 4; ++nt) {
                short8 bf8 = *(const short8*)&Ws[(nt*16 + ln15) * PSS + ks + quad*8];
                acc[nt] = __builtin_amdgcn_mfma_f32_16x16x32_bf16(af, bf8, acc[nt], 0, 0, 0);
            }
        }
        __syncthreads();
    }

    #pragma unroll
    for (int nt = 0; nt < 4; ++nt) {
        #pragma unroll
        for (int reg = 0; reg < 4; ++reg) {
            const int m = row0 + wv*16 + quad*4 + reg;
            const int n = col0 + nt*16 + ln15;
            float v = acc[nt][reg];
            if (!z) P1[(size_t)m * DIM + n] = v + bt[n];
            else    P2H[(size_t)m * DIM + n] = f2h(v);
        }
    }
}

// ---------------------------------------------------------------------------
// Kernel B: fused pairwise relu + fp16-MFMA GEMM + log_softmax(129).
// BARRIER-FREE K-loop: A-fragments built directly in registers
// (global 16B gather of P2H + LDS-broadcast dep row + v_pk_add/max_f16 —
// result is already MFMA-packed), B-fragments straight from L2-hot WpH.
// No hs/ws LDS tiles, no repack VALU, no K-loop __syncthreads.
// 256 threads = 4 waves; wave (mh,nh) owns the 48m x 64n quadrant.
// ---------------------------------------------------------------------------
__global__ __launch_bounds__(256, 3) void fused_kernel(
    const float* __restrict__ P1, const unsigned short* __restrict__ P2H,
    const unsigned short* __restrict__ WpH, const float* __restrict__ bp,
    float* __restrict__ out)
{
    const int db = blockIdx.x;      // d*16 + b
    const int b  = db & 15;

    __shared__ unsigned short drowH[DIM];      // dep row, fp16 (1 KB)
    __shared__ float pmx[96][2];               // softmax partials
    __shared__ float pl [96][2];

    const int tid  = threadIdx.x;       // 0..255
    const int lane = tid & 63;
    const int wv   = tid >> 6;          // 0..3
    const int ln15 = lane & 15;
    const int quad = lane >> 4;
    const int mh   = wv & 1;            // row half: [48*mh, 48*mh+48)
    const int nh   = wv >> 1;           // col half: [64*nh, 64*nh+64)

    // dep row f32 -> fp16 LDS (one-time)
    {
        float2 v = *(const float2*)(P1 + (size_t)db * DIM + tid*2);
        drowH[tid*2]   = f2h(v.x);
        drowH[tid*2+1] = f2h(v.y);
    }
    __syncthreads();

    // per-wave row/col base pointers (hoisted; loop offset folds to imm)
    const unsigned short* pA[3];
    #pragma unroll
    for (int mt = 0; mt < 3; ++mt)
        pA[mt] = P2H + ((size_t)(mh*48 + mt*16 + ln15) * BSZ + b) * DIM + quad*8;
    const unsigned short* pB[4];
    #pragma unroll
    for (int nt = 0; nt < 4; ++nt)
        pB[nt] = WpH + (size_t)(nh*64 + nt*16 + ln15) * DIM + quad*8;

    floatx4 acc[3][4];
    #pragma unroll
    for (int i = 0; i < 3; ++i)
        #pragma unroll
        for (int j = 0; j < 4; ++j) acc[i][j] = (floatx4){0.f,0.f,0.f,0.f};

    #pragma unroll 4
    for (int kk = 0; kk < DIM; kk += 32) {
        uint4 dv = *(const uint4*)&drowH[kk + quad*8];   // 8 fp16, quad-broadcast

        union { uint4 u; half8 h; } af[3], bf[4];
        #pragma unroll
        for (int mt = 0; mt < 3; ++mt) {
            uint4 pv = *(const uint4*)(pA[mt] + kk);
            af[mt].u.x = pk_max_h2(pk_add_h2(pv.x, dv.x), 0u);
            af[mt].u.y = pk_max_h2(pk_add_h2(pv.y, dv.y), 0u);
            af[mt].u.z = pk_max_h2(pk_add_h2(pv.z, dv.z), 0u);
            af[mt].u.w = pk_max_h2(pk_add_h2(pv.w, dv.w), 0u);
        }
        #pragma unroll
        for (int nt = 0; nt < 4; ++nt)
            bf[nt].u = *(const uint4*)(pB[nt] + kk);

        #pragma unroll
        for (int nt = 0; nt < 4; ++nt)
            #pragma unroll
            for (int mt = 0; mt < 3; ++mt)
                acc[mt][nt] = __builtin_amdgcn_mfma_f32_16x16x32_f16(
                    af[mt].h, bf[nt].h, acc[mt][nt], 0, 0, 0);
    }

    // ---- epilogue phase 1: per-quadrant softmax partials (no nil yet) ----
    float bpv[4];
    #pragma unroll
    for (int nt = 0; nt < 4; ++nt) bpv[nt] = bp[nh*64 + nt*16 + ln15];

    #pragma unroll
    for (int mt = 0; mt < 3; ++mt) {
        #pragma unroll
        for (int reg = 0; reg < 4; ++reg) {
            const int m = mh*48 + mt*16 + quad*4 + reg;
            float s[4];
            float mx = -1e30f;
            #pragma unroll
            for (int nt = 0; nt < 4; ++nt) {
                s[nt] = acc[mt][nt][reg] + bpv[nt];
                mx = fmaxf(mx, s[nt]);
            }
            #pragma unroll
            for (int msk = 1; msk < 16; msk <<= 1) mx = fmaxf(mx, __shfl_xor(mx, msk));
            float l = 0.f;
            #pragma unroll
            for (int nt = 0; nt < 4; ++nt) l += __expf(s[nt] - mx);
            #pragma unroll
            for (int msk = 1; msk < 16; msk <<= 1) l += __shfl_xor(l, msk);
            if (ln15 == 0) { pmx[m][nh] = mx; pl[m][nh] = l; }
        }
    }
    __syncthreads();

    // ---- epilogue phase 2: combine halves + nil, write out ----
    #pragma unroll
    for (int mt = 0; mt < 3; ++mt) {
        #pragma unroll
        for (int reg = 0; reg < 4; ++reg) {
            const int m = mh*48 + mt*16 + quad*4 + reg;
            const float mx0 = pmx[m][0], mx1 = pmx[m][1];
            const float l0  = pl[m][0],  l1  = pl[m][1];
            const float MX = fmaxf(fmaxf(mx0, mx1), 0.f);   // nil = 0 in max
            const float L  = l0 * __expf(mx0 - MX) + l1 * __expf(mx1 - MX)
                           + __expf(-MX);                    // nil term
            const float lse = MX + __logf(L);

            const size_t base = ((size_t)db * HEADS + m) * RELP;
            #pragma unroll
            for (int nt = 0; nt < 4; ++nt)
                out[base + 1 + nh*64 + nt*16 + ln15] = acc[mt][nt][reg] + bpv[nt] - lse;
            if (nh == 0 && ln15 == 0) out[base] = -lse;
        }
    }
}

extern "C" void kernel_launch(void* const* d_in, const int* in_sizes, int n_in,
                              void* d_out, int out_size, void* d_ws, size_t ws_size,
                              hipStream_t stream) {
    const float* outs  = (const float*)d_in[0];
    const float* graph = (const float*)d_in[1];
    const float* Wt    = (const float*)d_in[2];
    const float* bt    = (const float*)d_in[3];
    const float* Wp    = (const float*)d_in[4];
    const float* bp    = (const float*)d_in[5];
    float* out = (float*)d_out;

    // Workspace: 5,898,240 B — under the proven-safe 6.1 MB bound (R4 lesson).
    float* P1           = (float*)d_ws;                     // [1536][512] f32   (3 MB)
    unsigned short* P2H = (unsigned short*)(P1 + 786432);   // [1536][512] fp16  (1.5 MB)
    unsigned short* WpH = P2H + 786432;                     // [128][512]  fp16  (128 KB)
    unsigned short* WtB = WpH + 65536;                      // [512][1024] bf16  (1 MB)

    cvt_kernel<<<288, 256, 0, stream>>>(Wt, Wp, WtB, WpH);
    proj_kernel<<<dim3(DIM/64, (DEP*BSZ)/64, 2), 256, 0, stream>>>(
        outs, graph, WtB, bt, P1, P2H);
    fused_kernel<<<DEP*BSZ, 256, 0, stream>>>(P1, P2H, WpH, bp, out);
}

// Round 8
// 141.979 us; speedup vs baseline: 1.4449x; 1.4449x over previous
//
#include <hip/hip_runtime.h>
#include <hip/hip_bf16.h>
#include <math.h>

#define DEP   96
#define HEADS 96
#define BSZ   16
#define DIM   512
#define REL   128
#define RELP  129   // REL + nil

typedef __attribute__((ext_vector_type(8))) _Float16  half8;    // 8 fp16 (4 VGPRs)
typedef __attribute__((ext_vector_type(2))) __fp16    fp16x2;   // cvt_pkrtz return type
typedef __attribute__((ext_vector_type(4))) float     floatx4;

__device__ __forceinline__ unsigned short f2h(float x) {
    union { _Float16 h; unsigned short u; } c;
    c.h = (_Float16)x;                                   // v_cvt_f16_f32 (RNE)
    return c.u;
}
// two f32 -> packed 2xf16 in one v_cvt_pkrtz_f16_f32
__device__ __forceinline__ unsigned pk_f2h(float a, float b) {
    union { fp16x2 h; unsigned u; } c;
    c.h = __builtin_amdgcn_cvt_pkrtz(a, b);
    return c.u;
}
// packed fp16 add / relu (VOP3P)
__device__ __forceinline__ unsigned pk_add_h2(unsigned a, unsigned b) {
    unsigned r; asm("v_pk_add_f16 %0, %1, %2" : "=v"(r) : "v"(a), "v"(b)); return r;
}
__device__ __forceinline__ unsigned pk_max_h2(unsigned a, unsigned b) {
    unsigned r; asm("v_pk_max_f16 %0, %1, %2" : "=v"(r) : "v"(a), "v"(b)); return r;
}

// ---------------------------------------------------------------------------
// Kernel 0: weight conversion to fp16 (Wt for proj, Wp for fused).
// 73728 chunks x 8 elems: [0,65536) -> Wt, rest -> Wp.
// ---------------------------------------------------------------------------
__global__ __launch_bounds__(256) void cvt_kernel(
    const float* __restrict__ Wt, const float* __restrict__ Wp,
    unsigned short* __restrict__ WtH, unsigned short* __restrict__ WpH)
{
    const int chunk = blockIdx.x * 256 + threadIdx.x;
    const float* src; unsigned short* dst; int c;
    if (chunk < 65536) { src = Wt; dst = WtH; c = chunk; }
    else               { src = Wp; dst = WpH; c = chunk - 65536; }
    float4 a = *(const float4*)(src + (size_t)c * 8);
    float4 b = *(const float4*)(src + (size_t)c * 8 + 4);
    uint4 o;
    o.x = pk_f2h(a.x, a.y); o.y = pk_f2h(a.z, a.w);
    o.z = pk_f2h(b.x, b.y); o.w = pk_f2h(b.z, b.w);
    *(uint4*)(dst + (size_t)c * 8) = o;
}

#define PSS 72   // LDS row stride (fp16 elems): 144 B = 16B-aligned

// ---------------------------------------------------------------------------
// Kernel A: projections via fp16 MFMA. A cast-on-stage (v_cvt_pkrtz),
// Wt pre-cast fp16.
//   z=0: P1[m][n] = outs@Wt[:, :512]^T + bt   (f32 out)
//   z=1: P2H[m][n]= graph@Wt[:, 512:]^T       (fp16 out)
// 64x64 tile, BK=64, 256 threads = 4 waves; wave w owns m-rows [16w,16w+16).
// ---------------------------------------------------------------------------
__global__ __launch_bounds__(256) void proj_kernel(
    const float* __restrict__ outs, const float* __restrict__ graph,
    const unsigned short* __restrict__ WtH, const float* __restrict__ bt,
    float* __restrict__ P1, unsigned short* __restrict__ P2H)
{
    const int z = blockIdx.z;
    const float* A = z ? graph : outs;
    const int off  = z ? DIM : 0;
    const int row0 = blockIdx.y * 64;
    const int col0 = blockIdx.x * 64;

    __shared__ __align__(16) unsigned short As[64 * PSS];   // [m][k] fp16
    __shared__ __align__(16) unsigned short Ws[64 * PSS];   // [n][k] fp16

    const int tid  = threadIdx.x;
    const int lane = tid & 63;
    const int wv   = tid >> 6;          // 0..3
    const int ln15 = lane & 15;
    const int quad = lane >> 4;

    floatx4 acc[4];
    #pragma unroll
    for (int nt = 0; nt < 4; ++nt) acc[nt] = (floatx4){0.f,0.f,0.f,0.f};

    for (int kt = 0; kt < DIM; kt += 64) {
        // A: f32 load + packed RTZ cast to fp16 LDS (8 elems/slot, 2 slots)
        #pragma unroll
        for (int q = 0; q < 2; ++q) {
            const int slot = q*256 + tid;       // 0..511
            const int r  = slot >> 3;           // 0..63
            const int e8 = (slot & 7) * 8;
            const float* p = A + (size_t)(row0 + r) * DIM + kt + e8;
            float4 va = *(const float4*)p;
            float4 vb = *(const float4*)(p + 4);
            uint4 o;
            o.x = pk_f2h(va.x, va.y); o.y = pk_f2h(va.z, va.w);
            o.z = pk_f2h(vb.x, vb.y); o.w = pk_f2h(vb.z, vb.w);
            *(uint4*)&As[r * PSS + e8] = o;
        }
        // Wt: pure uint4 copy (pre-cast fp16)
        #pragma unroll
        for (int q = 0; q < 2; ++q) {
            const int slot = q*256 + tid;       // 0..511
            const int r  = slot >> 3;           // 0..63
            const int e8 = (slot & 7) * 8;
            *(uint4*)&Ws[r * PSS + e8] =
                *(const uint4*)(WtH + (size_t)(col0 + r) * (2*DIM) + off + kt + e8);
        }
        __syncthreads();
        #pragma unroll
        for (int ks = 0; ks < 64; ks += 32) {
            half8 af = *(const half8*)&As[(wv*16 + ln15) * PSS + ks + quad*8];
            #pragma unroll
            for (int nt = 0; nt < 4; ++nt) {
                half8 bf8 = *(const half8*)&Ws[(nt*16 + ln15) * PSS + ks + quad*8];
                acc[nt] = __builtin_amdgcn_mfma_f32_16x16x32_f16(af, bf8, acc[nt], 0, 0, 0);
            }
        }
        __syncthreads();
    }

    #pragma unroll
    for (int nt = 0; nt < 4; ++nt) {
        #pragma unroll
        for (int reg = 0; reg < 4; ++reg) {
            const int m = row0 + wv*16 + quad*4 + reg;
            const int n = col0 + nt*16 + ln15;
            float v = acc[nt][reg];
            if (!z) P1[(size_t)m * DIM + n] = v + bt[n];
            else    P2H[(size_t)m * DIM + n] = f2h(v);
        }
    }
}

// ---------------------------------------------------------------------------
// Kernel B: fused pairwise relu + fp16-MFMA GEMM + log_softmax(129).
// R5's staged/coalesced structure (R6's register-direct gathers were
// VMEM-address-bound: 16 lines/inst) + packed-fp16 staging math:
// per 8 elems of h: uint4 load + 4 pk_add + 4 pk_max + ds_write_b128
// (was ~40 VALU insts of bf16 unpack/repack).
// 256 threads = 4 waves; wave (mh,nh) owns the 48m x 64n quadrant.
// ---------------------------------------------------------------------------
#define HSS 72
#define WSS 72

__global__ __launch_bounds__(256, 4) void fused_kernel(
    const float* __restrict__ P1, const unsigned short* __restrict__ P2H,
    const unsigned short* __restrict__ WpH, const float* __restrict__ bp,
    float* __restrict__ out)
{
    const int db = blockIdx.x;      // d*16 + b
    const int b  = db & 15;

    __shared__ __align__(16) unsigned short drowH[DIM];     // dep row fp16
    __shared__ __align__(16) unsigned short hs[96 * HSS];   // h tile  [m][k]
    __shared__ __align__(16) unsigned short ws[128 * WSS];  // Wp tile [n][k]
    __shared__ float pmx[96][2];     // softmax partials per (row, col-half)
    __shared__ float pl [96][2];

    const int tid  = threadIdx.x;       // 0..255
    const int lane = tid & 63;
    const int wv   = tid >> 6;          // 0..3
    const int ln15 = lane & 15;
    const int quad = lane >> 4;
    const int mh   = wv & 1;            // row half: [48*mh, 48*mh+48)
    const int nh   = wv >> 1;           // col half: [64*nh, 64*nh+64)

    // dep row f32 -> fp16 (one-time)
    {
        float2 v = *(const float2*)(P1 + (size_t)db * DIM + tid*2);
        *(unsigned*)&drowH[tid*2] = pk_f2h(v.x, v.y);
    }
    __syncthreads();

    floatx4 acc[3][4];
    #pragma unroll
    for (int i = 0; i < 3; ++i)
        #pragma unroll
        for (int j = 0; j < 4; ++j) acc[i][j] = (floatx4){0.f,0.f,0.f,0.f};

    for (int kt = 0; kt < DIM; kt += 64) {
        // ---- stage hs[h][e] = fp16 relu(drow[e] + P2H[h,b,e]), 96x64 ----
        #pragma unroll
        for (int q = 0; q < 3; ++q) {
            const int slot = q*256 + tid;        // 0..767
            const int h  = slot >> 3;            // 0..95
            const int e8 = (slot & 7) * 8;
            uint4 pv = *(const uint4*)(P2H + ((size_t)h * BSZ + b) * DIM + kt + e8);
            uint4 dv = *(const uint4*)&drowH[kt + e8];
            uint4 o;
            o.x = pk_max_h2(pk_add_h2(pv.x, dv.x), 0u);
            o.y = pk_max_h2(pk_add_h2(pv.y, dv.y), 0u);
            o.z = pk_max_h2(pk_add_h2(pv.z, dv.z), 0u);
            o.w = pk_max_h2(pk_add_h2(pv.w, dv.w), 0u);
            *(uint4*)&hs[h * HSS + e8] = o;
        }
        // ---- stage ws[r][e] = WpH[r][kt+e], 128x64 (B-operand layout) ----
        #pragma unroll
        for (int q = 0; q < 4; ++q) {
            const int slot = q*256 + tid;        // 0..1023
            const int r = slot >> 3;
            const int g = (slot & 7) * 8;
            *(uint4*)&ws[r * WSS + g] =
                *(const uint4*)(WpH + (size_t)r * DIM + kt + g);
        }
        __syncthreads();

        #pragma unroll
        for (int ks = 0; ks < 64; ks += 32) {
            half8 af[3], bf8[4];
            #pragma unroll
            for (int mt = 0; mt < 3; ++mt)
                af[mt] = *(const half8*)&hs[(mh*48 + mt*16 + ln15) * HSS + ks + quad*8];
            #pragma unroll
            for (int nt = 0; nt < 4; ++nt)
                bf8[nt] = *(const half8*)&ws[(nh*64 + nt*16 + ln15) * WSS + ks + quad*8];
            #pragma unroll
            for (int nt = 0; nt < 4; ++nt)
                #pragma unroll
                for (int mt = 0; mt < 3; ++mt)
                    acc[mt][nt] = __builtin_amdgcn_mfma_f32_16x16x32_f16(
                        af[mt], bf8[nt], acc[mt][nt], 0, 0, 0);
        }
        __syncthreads();
    }

    // ---- epilogue phase 1: per-quadrant softmax partials (no nil yet) ----
    float bpv[4];
    #pragma unroll
    for (int nt = 0; nt < 4; ++nt) bpv[nt] = bp[nh*64 + nt*16 + ln15];

    #pragma unroll
    for (int mt = 0; mt < 3; ++mt) {
        #pragma unroll
        for (int reg = 0; reg < 4; ++reg) {
            const int m = mh*48 + mt*16 + quad*4 + reg;
            float s[4];
            float mx = -1e30f;
            #pragma unroll
            for (int nt = 0; nt < 4; ++nt) {
                s[nt] = acc[mt][nt][reg] + bpv[nt];
                mx = fmaxf(mx, s[nt]);
            }
            #pragma unroll
            for (int msk = 1; msk < 16; msk <<= 1) mx = fmaxf(mx, __shfl_xor(mx, msk));
            float l = 0.f;
            #pragma unroll
            for (int nt = 0; nt < 4; ++nt) l += __expf(s[nt] - mx);
            #pragma unroll
            for (int msk = 1; msk < 16; msk <<= 1) l += __shfl_xor(l, msk);
            if (ln15 == 0) { pmx[m][nh] = mx; pl[m][nh] = l; }
        }
    }
    __syncthreads();

    // ---- epilogue phase 2: combine halves + nil, write out ----
    #pragma unroll
    for (int mt = 0; mt < 3; ++mt) {
        #pragma unroll
        for (int reg = 0; reg < 4; ++reg) {
            const int m = mh*48 + mt*16 + quad*4 + reg;
            const float mx0 = pmx[m][0], mx1 = pmx[m][1];
            const float l0  = pl[m][0],  l1  = pl[m][1];
            const float MX = fmaxf(fmaxf(mx0, mx1), 0.f);   // nil = 0 in max
            const float L  = l0 * __expf(mx0 - MX) + l1 * __expf(mx1 - MX)
                           + __expf(-MX);                    // nil term
            const float lse = MX + __logf(L);

            const size_t base = ((size_t)db * HEADS + m) * RELP;
            #pragma unroll
            for (int nt = 0; nt < 4; ++nt)
                out[base + 1 + nh*64 + nt*16 + ln15] = acc[mt][nt][reg] + bpv[nt] - lse;
            if (nh == 0 && ln15 == 0) out[base] = -lse;
        }
    }
}

extern "C" void kernel_launch(void* const* d_in, const int* in_sizes, int n_in,
                              void* d_out, int out_size, void* d_ws, size_t ws_size,
                              hipStream_t stream) {
    const float* outs  = (const float*)d_in[0];
    const float* graph = (const float*)d_in[1];
    const float* Wt    = (const float*)d_in[2];
    const float* bt    = (const float*)d_in[3];
    const float* Wp    = (const float*)d_in[4];
    const float* bp    = (const float*)d_in[5];
    float* out = (float*)d_out;

    // Workspace: 5,875,712 B — under the proven-safe 6.1 MB bound (R4 lesson).
    float* P1           = (float*)d_ws;                     // [1536][512] f32   (3 MB)
    unsigned short* P2H = (unsigned short*)(P1 + 786432);   // [1536][512] fp16  (1.5 MB)
    unsigned short* WpH = P2H + 786432;                     // [128][512]  fp16  (128 KB)
    unsigned short* WtH = WpH + 65536;                      // [512][1024] fp16  (1 MB)

    cvt_kernel<<<288, 256, 0, stream>>>(Wt, Wp, WtH, WpH);
    proj_kernel<<<dim3(DIM/64, (DEP*BSZ)/64, 2), 256, 0, stream>>>(
        outs, graph, WtH, bt, P1, P2H);
    fused_kernel<<<DEP*BSZ, 256, 0, stream>>>(P1, P2H, WpH, bp, out);
}